// Round 7
// baseline (153.427 us; speedup 1.0000x reference)
//
#include <hip/hip_runtime.h>
#include <hip/hip_bf16.h>

// Problem: B=4, L=2048, E=512, D=128
//   dep[b,l,d]  = sum_e emb[b,l,e] * W[d,e]
//   dist[b,i,j] = sq[i] + sq[j] - 2 * dep_b . dep_b
// d_out = dep (8192*128 f32) ++ distances (4*2048*2048 f32)
//
// Round 7 ledger:
//   R2->R4: nontemporal stores = +7us (reverted)
//   R1->R2: gram no-LDS        = +6us (reverted)
//   R4->R5: swap + float4      = -11us
//   R5->R6: J-only kP2 rework  = +1us (kept only for 4/CU occupancy here)
//   NEW: single cooperative kernel, producer-consumer flags per batch
//        (no grid.sync), K-split phase1 (no redundant emb cvt), phase
//        overlap: batch-0 dist tiles start while batch 1-3 dep still runs.

typedef __attribute__((ext_vector_type(8))) short  short8;   // 8 bf16
typedef __attribute__((ext_vector_type(4))) float  floatx4;  // MFMA C/D frag

#define B_  4
#define L_  2048
#define E_  512
#define D_  128
#define M_  (B_*L_)   // 8192
#define NPROD 512     // phase-1 producer blocks, 16 rows each
#define NBLK  1024    // total blocks = dist tiles, 4/CU co-resident

__device__ __forceinline__ unsigned short f2bfu(float x) {
    __hip_bfloat16 h = __float2bfloat16(x);          // HW RNE
    union { __hip_bfloat16 h; unsigned short u; } c; c.h = h; return c.u;
}
__device__ __forceinline__ float bfu2f(unsigned short u) {
    union { unsigned u32; float f; } c; c.u32 = ((unsigned)u) << 16; return c.f;
}
__device__ __forceinline__ short8 cvt8(const float* p) {
    float4 x = *reinterpret_cast<const float4*>(p);
    float4 y = *reinterpret_cast<const float4*>(p + 4);
    short8 t;
    t[0] = (short)f2bfu(x.x); t[1] = (short)f2bfu(x.y);
    t[2] = (short)f2bfu(x.z); t[3] = (short)f2bfu(x.w);
    t[4] = (short)f2bfu(y.x); t[5] = (short)f2bfu(y.y);
    t[6] = (short)f2bfu(y.z); t[7] = (short)f2bfu(y.w);
    return t;
}

// ---------------- kW: W f32 -> bf16 once ------------------------------------
__global__ __launch_bounds__(256)
void kW(const float* __restrict__ W, unsigned short* __restrict__ Wb)
{
    int i = (blockIdx.x * 256 + threadIdx.x) * 4;     // 64 blocks cover 65536
    float4 v = *reinterpret_cast<const float4*>(W + i);
    ushort4 u;
    u.x = f2bfu(v.x); u.y = f2bfu(v.y); u.z = f2bfu(v.z); u.w = f2bfu(v.w);
    *reinterpret_cast<ushort4*>(Wb + i) = u;
}

// ---------------- phase 1: 16 dep rows, K-split across 4 waves --------------
// Wave w covers K in [w*128, w*128+128): converts each emb element ONCE.
// Swapped MFMA (A=W-frag, B=emb-frag): lane(l15,lg) holds rows m0+l15,
// d-cols dg*16+lg*4+j. Partials -> LDS [4][16][132] -> f32 add -> output.
__device__ __forceinline__ void phase1(int bid, int tid,
    const float* __restrict__ emb, const unsigned short* __restrict__ Wb,
    float* __restrict__ dep_out, unsigned short* __restrict__ dep_b16,
    float* __restrict__ sq, char* smem)
{
    float (*sc)[16][132] = reinterpret_cast<float (*)[16][132]>(smem); // 33792 B
    const int lane = tid & 63, w = tid >> 6;
    const int l15 = lane & 15, lg = lane >> 4;
    const long m0 = (long)bid * 16;

    floatx4 acc[8];
    #pragma unroll
    for (int dg = 0; dg < 8; ++dg) acc[dg] = (floatx4){0.f, 0.f, 0.f, 0.f};

    const float* ar = emb + (m0 + l15) * E_ + w * 128;
    const unsigned short* wb = Wb + l15 * E_ + w * 128;

    #pragma unroll
    for (int k0 = 0; k0 < 128; k0 += 32) {
        const int kc = k0 + lg * 8;
        short8 bfm = cvt8(ar + kc);
        #pragma unroll
        for (int dg = 0; dg < 8; ++dg) {
            short8 af = *reinterpret_cast<const short8*>(wb + dg * 16 * E_ + kc);
            acc[dg] = __builtin_amdgcn_mfma_f32_16x16x32_bf16(af, bfm, acc[dg], 0, 0, 0);
        }
    }
    #pragma unroll
    for (int dg = 0; dg < 8; ++dg)
        *reinterpret_cast<floatx4*>(&sc[w][l15][dg * 16 + lg * 4]) = acc[dg];
    __syncthreads();

    // reduce 4 K-partials; thread t -> row t>>4, cols (t&15)*8 .. +7
    const int r = tid >> 4, i = tid & 15;
    const long m = m0 + r;
    float p = 0.f;
    short8 u8;
    #pragma unroll
    for (int h = 0; h < 2; ++h) {
        floatx4 v = *reinterpret_cast<const floatx4*>(&sc[0][r][i * 8 + h * 4]);
        v += *reinterpret_cast<const floatx4*>(&sc[1][r][i * 8 + h * 4]);
        v += *reinterpret_cast<const floatx4*>(&sc[2][r][i * 8 + h * 4]);
        v += *reinterpret_cast<const floatx4*>(&sc[3][r][i * 8 + h * 4]);
        *reinterpret_cast<floatx4*>(dep_out + m * D_ + i * 8 + h * 4) = v;
        #pragma unroll
        for (int c = 0; c < 4; ++c) {
            unsigned short u = f2bfu(v[c]);
            u8[h * 4 + c] = (short)u;
            float vb = bfu2f(u);
            p += vb * vb;           // sq from bf16-rounded dep (matches gram)
        }
    }
    *reinterpret_cast<short8*>(dep_b16 + m * D_ + i * 8) = u8;
    p += __shfl_xor(p, 1); p += __shfl_xor(p, 2);
    p += __shfl_xor(p, 4); p += __shfl_xor(p, 8);
    if (i == 0) sq[m] = p;
    __syncthreads();                // smem safe for phase2 reuse
}

// ---------------- phase 2: one 128x128 dist tile (J-only LDS) ---------------
__device__ __forceinline__ void phase2(int bidx, int tid,
    const unsigned short* __restrict__ dep_b16, const float* __restrict__ sq,
    float* __restrict__ dist, int* flags, char* smem)
{
    unsigned short (*Js)[136] = reinterpret_cast<unsigned short (*)[136]>(smem);

    const int lane = tid & 63;
    const int wave = tid >> 6;
    const int wr = wave >> 1, wc = wave & 1;
    const int l15 = lane & 15, lg = lane >> 4;

    // bijective XCD swizzle (1024 % 8 == 0)
    const int swz = (bidx & 7) * 128 + (bidx >> 3);
    const int b  = swz >> 8;
    const int i0 = ((swz >> 4) & 15) * 128;
    const int j0 = (swz & 15) * 128;

    if (flags) {                    // wait until batch b's 128 producers done
        if (tid == 0) {
            while (__hip_atomic_load(flags + b, __ATOMIC_ACQUIRE,
                                     __HIP_MEMORY_SCOPE_AGENT) < 128)
                __builtin_amdgcn_s_sleep(8);
        }
        __syncthreads();
    }

    const unsigned short* depb = dep_b16 + (long)b * L_ * D_;

    #pragma unroll
    for (int jj = 0; jj < 8; ++jj) {
        int chunk = tid + 256 * jj;               // 0..2047, fully coalesced
        int row = chunk >> 4, c8 = chunk & 15;
        *reinterpret_cast<short8*>(&Js[row][c8 * 8]) =
            *reinterpret_cast<const short8*>(depb + (long)(j0 + row) * D_ + c8 * 8);
    }

    const unsigned short* ibase = depb + (long)(i0 + wr * 64 + l15) * D_ + lg * 8;
    short8 af[2][4];
    #pragma unroll
    for (int kk = 0; kk < 4; ++kk)                 // prefetch mi=0
        af[0][kk] = *reinterpret_cast<const short8*>(ibase + kk * 32);

    const float* sqb = sq + b * L_;
    float sri[4];
    #pragma unroll
    for (int mi = 0; mi < 4; ++mi)
        sri[mi] = sqb[i0 + wr * 64 + mi * 16 + l15];
    floatx4 sqj[4];
    #pragma unroll
    for (int ni = 0; ni < 4; ++ni)
        sqj[ni] = *reinterpret_cast<const floatx4*>(sqb + j0 + wc * 64 + ni * 16 + lg * 4);

    __syncthreads();

    float* db = dist + (long)b * L_ * L_;
    #pragma unroll
    for (int mi = 0; mi < 4; ++mi) {
        if (mi < 3) {
            #pragma unroll
            for (int kk = 0; kk < 4; ++kk)
                af[(mi + 1) & 1][kk] = *reinterpret_cast<const short8*>(
                    ibase + (long)(mi + 1) * 16 * D_ + kk * 32);
        }
        floatx4 acc[4];
        #pragma unroll
        for (int ni = 0; ni < 4; ++ni)
            acc[ni] = (floatx4){0.f, 0.f, 0.f, 0.f};
        #pragma unroll
        for (int ni = 0; ni < 4; ++ni) {
            #pragma unroll
            for (int kk = 0; kk < 4; ++kk) {
                short8 bf = *reinterpret_cast<const short8*>(
                    &Js[wc * 64 + ni * 16 + l15][kk * 32 + lg * 8]);
                acc[ni] = __builtin_amdgcn_mfma_f32_16x16x32_bf16(
                    bf, af[mi & 1][kk], acc[ni], 0, 0, 0);   // swapped A<->B
            }
        }
        const long i = i0 + wr * 64 + mi * 16 + l15;
        #pragma unroll
        for (int ni = 0; ni < 4; ++ni) {
            const int jb = j0 + wc * 64 + ni * 16 + lg * 4;
            floatx4 v;
            #pragma unroll
            for (int jj = 0; jj < 4; ++jj)
                v[jj] = sri[mi] + sqj[ni][jj] - 2.0f * acc[ni][jj];
            *reinterpret_cast<floatx4*>(db + i * L_ + jb) = v;
        }
    }
}

// ---------------- cooperative mega-kernel -----------------------------------
__global__ __launch_bounds__(256, 4)
void kMega(const float* __restrict__ emb, const unsigned short* __restrict__ Wb,
           float* __restrict__ dep_out, unsigned short* __restrict__ dep_b16,
           float* __restrict__ sq, float* __restrict__ dist, int* flags)
{
    __shared__ __align__(16) char smem[34816];
    const int bid = blockIdx.x, tid = threadIdx.x;
    if (bid < NPROD) {
        phase1(bid, tid, emb, Wb, dep_out, dep_b16, sq, smem);
        if (tid == 0)
            __hip_atomic_fetch_add(flags + (bid >> 7), 1, __ATOMIC_RELEASE,
                                   __HIP_MEMORY_SCOPE_AGENT);
    }
    phase2(bid, tid, dep_b16, sq, dist, flags, smem);
}

// ---------------- fallback standalone kernels -------------------------------
__global__ __launch_bounds__(256)
void kP1s(const float* __restrict__ emb, const unsigned short* __restrict__ Wb,
          float* __restrict__ dep_out, unsigned short* __restrict__ dep_b16,
          float* __restrict__ sq)
{
    __shared__ __align__(16) char smem[33792];
    phase1(blockIdx.x, threadIdx.x, emb, Wb, dep_out, dep_b16, sq, smem);
}

__global__ __launch_bounds__(256, 4)
void kP2s(const unsigned short* __restrict__ dep_b16, const float* __restrict__ sq,
          float* __restrict__ dist)
{
    __shared__ __align__(16) char smem[34816];
    phase2(blockIdx.x, threadIdx.x, dep_b16, sq, dist, nullptr, smem);
}

extern "C" void kernel_launch(void* const* d_in, const int* in_sizes, int n_in,
                              void* d_out, int out_size, void* d_ws, size_t ws_size,
                              hipStream_t stream)
{
    const float* emb = (const float*)d_in[0];   // [B,L,E] f32
    const float* W   = (const float*)d_in[1];   // [D,E]   f32

    float* dep_out = (float*)d_out;                       // [B*L, D]
    float* dist    = dep_out + (size_t)M_ * D_;           // [B, L, L]

    char* ws = (char*)d_ws;
    unsigned short* dep_b16 = (unsigned short*)ws;            ws += (size_t)M_ * D_ * 2;  // 2 MB
    float* sq               = (float*)ws;                     ws += (size_t)M_ * 4;       // 32 KB
    unsigned short* Wb      = (unsigned short*)ws;            ws += (size_t)D_ * E_ * 2;  // 128 KB
    int* flags              = (int*)ws;                                                   // 16 B

    hipMemsetAsync(flags, 0, B_ * sizeof(int), stream);
    hipLaunchKernelGGL(kW, dim3((D_ * E_) / (256 * 4)), dim3(256), 0, stream, W, Wb);

    void* args[7] = { (void*)&emb, (void*)&Wb, (void*)&dep_out,
                      (void*)&dep_b16, (void*)&sq, (void*)&dist, (void*)&flags };
    hipError_t err = hipLaunchCooperativeKernel((const void*)kMega,
                                                dim3(NBLK), dim3(256),
                                                args, 0, stream);
    if (err != hipSuccess) {
        hipLaunchKernelGGL(kP1s, dim3(NPROD), dim3(256), 0, stream,
                           emb, Wb, dep_out, dep_b16, sq);
        hipLaunchKernelGGL(kP2s, dim3(NBLK), dim3(256), 0, stream,
                           dep_b16, sq, dist);
    }
}

// Round 8
// 48.557 us; speedup vs baseline: 3.1597x; 3.1597x over previous
//
#include <hip/hip_runtime.h>
#include <hip/hip_bf16.h>

// Problem: B=4, L=2048, E=512, D=128
//   dep[b,l,d]  = sum_e emb[b,l,e] * W[d,e]
//   dist[b,i,j] = sq[i] + sq[j] - 2 * dep_b . dep_b
// d_out = dep (8192*128 f32) ++ distances (4*2048*2048 f32)
//
// Round 8 ledger:
//   R2->R4: nontemporal stores       = +7us (reverted)
//   R1->R2: gram no-LDS              = +6us (reverted)
//   R4->R5: swap + float4 stores     = -11us
//   R5->R6: J-only LDS @4/CU         = +1us (occupancy NOT the limiter)
//   R7: coop + agent-scope spin      = +104us (L2 inv/wb storm; never again)
//   NEW: kP2 epilogue routes each 32x128 slice through LDS so every store
//        instruction writes 8 FULL 128B lines (was 16 scattered 64B chunks).

typedef __attribute__((ext_vector_type(8))) short  short8;   // 8 bf16
typedef __attribute__((ext_vector_type(4))) float  floatx4;  // MFMA C/D frag
typedef __attribute__((ext_vector_type(4))) unsigned short ushortx4;

#define B_  4
#define L_  2048
#define E_  512
#define D_  128
#define M_  (B_*L_)   // 8192

__device__ __forceinline__ unsigned short f2bfu(float x) {
    __hip_bfloat16 h = __float2bfloat16(x);          // HW RNE
    union { __hip_bfloat16 h; unsigned short u; } c; c.h = h; return c.u;
}
__device__ __forceinline__ float bfu2f(unsigned short u) {
    union { unsigned u32; float f; } c; c.u32 = ((unsigned)u) << 16; return c.f;
}
__device__ __forceinline__ short8 cvt8(const float* p) {
    float4 x = *reinterpret_cast<const float4*>(p);
    float4 y = *reinterpret_cast<const float4*>(p + 4);
    short8 t;
    t[0] = (short)f2bfu(x.x); t[1] = (short)f2bfu(x.y);
    t[2] = (short)f2bfu(x.z); t[3] = (short)f2bfu(x.w);
    t[4] = (short)f2bfu(y.x); t[5] = (short)f2bfu(y.y);
    t[6] = (short)f2bfu(y.z); t[7] = (short)f2bfu(y.w);
    return t;
}

// ---------------- kW: W f32 -> bf16 once ------------------------------------
__global__ __launch_bounds__(256)
void kW(const float* __restrict__ W, unsigned short* __restrict__ Wb)
{
    int i = (blockIdx.x * 256 + threadIdx.x) * 4;     // 64 blocks cover 65536
    float4 v = *reinterpret_cast<const float4*>(W + i);
    ushort4 u;
    u.x = f2bfu(v.x); u.y = f2bfu(v.y); u.z = f2bfu(v.z); u.w = f2bfu(v.w);
    *reinterpret_cast<ushort4*>(Wb + i) = u;
}

// ---------------- kP1: dep (f32+bf16) + sq; 16 rows per block ---------------
// Swapped operands (A=W-frag, B=emb-frag): lane holds 4 consecutive d-cols
// of one m-row -> float4/ushort4 stores. [unchanged from R6]
__global__ __launch_bounds__(256)
void kP1(const float* __restrict__ emb, const unsigned short* __restrict__ Wb,
         float* __restrict__ dep_out, unsigned short* __restrict__ dep_b16,
         float* __restrict__ sq)
{
    __shared__ float pws[16][4];
    const int tid  = threadIdx.x;
    const int lane = tid & 63, wave = tid >> 6;      // wave owns d-cols wave*32..+31
    const int l15 = lane & 15, lg = lane >> 4;
    const long m0 = (long)blockIdx.x * 16;

    floatx4 acc[2] = { (floatx4){0.f,0.f,0.f,0.f}, (floatx4){0.f,0.f,0.f,0.f} };
    const float* ar = emb + (m0 + l15) * E_;               // B-operand (emb row)
    const unsigned short* w0 = Wb + (wave * 32 + l15) * E_;
    const unsigned short* w1 = Wb + (wave * 32 + 16 + l15) * E_;

    #pragma unroll
    for (int k0 = 0; k0 < E_; k0 += 32) {
        const int kc = k0 + lg * 8;
        short8 bfm = cvt8(ar + kc);
        short8 af0 = *reinterpret_cast<const short8*>(w0 + kc);
        short8 af1 = *reinterpret_cast<const short8*>(w1 + kc);
        acc[0] = __builtin_amdgcn_mfma_f32_16x16x32_bf16(af0, bfm, acc[0], 0, 0, 0);
        acc[1] = __builtin_amdgcn_mfma_f32_16x16x32_bf16(af1, bfm, acc[1], 0, 0, 0);
    }

    const long m = m0 + l15;
    float p = 0.f;
    #pragma unroll
    for (int ni = 0; ni < 2; ++ni) {
        const int dbase = wave * 32 + ni * 16 + lg * 4;
        floatx4  v;
        ushortx4 u;
        #pragma unroll
        for (int j = 0; j < 4; ++j) {
            v[j] = acc[ni][j];
            u[j] = f2bfu(v[j]);
            float vb = bfu2f(u[j]);
            p += vb * vb;               // sq from bf16-rounded dep (matches gram)
        }
        *reinterpret_cast<floatx4*>(dep_out + m * D_ + dbase)  = v;
        *reinterpret_cast<ushortx4*>(dep_b16 + m * D_ + dbase) = u;
    }
    p += __shfl_xor(p, 16);
    p += __shfl_xor(p, 32);
    if (lane < 16) pws[lane][wave] = p;
    __syncthreads();
    if (tid < 16)
        sq[m0 + tid] = pws[tid][0] + pws[tid][1] + pws[tid][2] + pws[tid][3];
}

// ---------------- kP2 v4: dist tile 128x128, full-line stores ---------------
// J-only LDS (34.8KB) + 16.9KB transpose buffer -> 3 blocks/CU.
// Per mi: 16 MFMAs -> slice (32 rows x 128 cols, pre-scaled -2g) into LDS ->
// barrier -> readout adds sq_i+sq_j and stores so each instruction writes
// 8 FULL 128B lines (8 rows x 128B contiguous).
__global__ __launch_bounds__(256, 3)
void kP2(const unsigned short* __restrict__ dep_b16, const float* __restrict__ sq,
         float* __restrict__ dist)
{
    __shared__ __align__(16) unsigned short Js[128][136];   // 34816 B
    __shared__ __align__(16) float sc[32][132];             // 16896 B (528B rows, 16B-mult)

    const int tid  = threadIdx.x;
    const int lane = tid & 63;
    const int wave = tid >> 6;
    const int wr = wave >> 1, wc = wave & 1;
    const int l15 = lane & 15, lg = lane >> 4;

    // bijective XCD swizzle (1024 % 8 == 0)
    const int swz = (blockIdx.x & 7) * 128 + (blockIdx.x >> 3);
    const int b  = swz >> 8;
    const int i0 = ((swz >> 4) & 15) * 128;
    const int j0 = (swz & 15) * 128;
    const unsigned short* depb = dep_b16 + (long)b * L_ * D_;

    // stage J tile (32 KB), fully coalesced
    #pragma unroll
    for (int jj = 0; jj < 8; ++jj) {
        int chunk = tid + 256 * jj;               // 0..2047
        int row = chunk >> 4, c8 = chunk & 15;
        *reinterpret_cast<short8*>(&Js[row][c8 * 8]) =
            *reinterpret_cast<const short8*>(depb + (long)(j0 + row) * D_ + c8 * 8);
    }

    const unsigned short* ibase = depb + (long)(i0 + wr * 64 + l15) * D_ + lg * 8;
    short8 af[2][4];
    #pragma unroll
    for (int kk = 0; kk < 4; ++kk)                 // prefetch mi=0
        af[0][kk] = *reinterpret_cast<const short8*>(ibase + kk * 32);

    const float* sqb = sq + b * L_;
    float* db = dist + (long)b * L_ * L_;

    // readout mapping: thread t -> local row t>>3 (0..31); within-row float
    // offset c4 + q*32 (q=0..3) -> per-instr lanes cover 8 rows x 128B lines.
    const int lr = tid >> 3;
    const int c4 = (tid & 7) * 4;

    __syncthreads();

    #pragma unroll
    for (int mi = 0; mi < 4; ++mi) {
        if (mi < 3) {                               // prefetch next I-frags
            #pragma unroll
            for (int kk = 0; kk < 4; ++kk)
                af[(mi + 1) & 1][kk] = *reinterpret_cast<const short8*>(
                    ibase + (long)(mi + 1) * 16 * D_ + kk * 32);
        }
        floatx4 acc[4];
        #pragma unroll
        for (int ni = 0; ni < 4; ++ni)
            acc[ni] = (floatx4){0.f, 0.f, 0.f, 0.f};
        #pragma unroll
        for (int ni = 0; ni < 4; ++ni) {
            #pragma unroll
            for (int kk = 0; kk < 4; ++kk) {
                short8 bf = *reinterpret_cast<const short8*>(
                    &Js[wc * 64 + ni * 16 + l15][kk * 32 + lg * 8]);
                acc[ni] = __builtin_amdgcn_mfma_f32_16x16x32_bf16(
                    bf, af[mi & 1][kk], acc[ni], 0, 0, 0);   // swapped A<->B
            }
        }
        // slice into LDS, pre-scaled by -2 (local row = wr*16+l15)
        #pragma unroll
        for (int ni = 0; ni < 4; ++ni)
            *reinterpret_cast<floatx4*>(&sc[wr * 16 + l15][wc * 64 + ni * 16 + lg * 4])
                = acc[ni] * -2.0f;
        __syncthreads();

        // readout: global row = i0 + (lr>>4)*64 + mi*16 + (lr&15)
        const long grow = i0 + (lr >> 4) * 64 + mi * 16 + (lr & 15);
        const float sri = sqb[grow];
        #pragma unroll
        for (int q = 0; q < 4; ++q) {
            const int cf = c4 + q * 32;
            floatx4 sj = *reinterpret_cast<const floatx4*>(sqb + j0 + cf);
            floatx4 g  = *reinterpret_cast<const floatx4*>(&sc[lr][cf]);
            floatx4 v;
            #pragma unroll
            for (int jj = 0; jj < 4; ++jj)
                v[jj] = sri + sj[jj] + g[jj];
            *reinterpret_cast<floatx4*>(db + grow * L_ + j0 + cf) = v;
        }
        if (mi < 3) __syncthreads();                // sc reusable next mi
    }
}

extern "C" void kernel_launch(void* const* d_in, const int* in_sizes, int n_in,
                              void* d_out, int out_size, void* d_ws, size_t ws_size,
                              hipStream_t stream)
{
    const float* emb = (const float*)d_in[0];   // [B,L,E] f32
    const float* W   = (const float*)d_in[1];   // [D,E]   f32

    float* dep_out = (float*)d_out;                       // [B*L, D]
    float* dist    = dep_out + (size_t)M_ * D_;           // [B, L, L]

    char* ws = (char*)d_ws;
    unsigned short* dep_b16 = (unsigned short*)ws;            ws += (size_t)M_ * D_ * 2;  // 2 MB
    float* sq               = (float*)ws;                     ws += (size_t)M_ * 4;       // 32 KB
    unsigned short* Wb      = (unsigned short*)ws;                                        // 128 KB

    hipLaunchKernelGGL(kW,  dim3((D_ * E_) / (256 * 4)), dim3(256), 0, stream, W, Wb);
    hipLaunchKernelGGL(kP1, dim3(M_ / 16), dim3(256), 0, stream,
                       emb, Wb, dep_out, dep_b16, sq);
    hipLaunchKernelGGL(kP2, dim3(16 * 16 * B_), dim3(256), 0, stream,
                       dep_b16, sq, dist);
}